// Round 8
// baseline (281.454 us; speedup 1.0000x reference)
//
#include <hip/hip_runtime.h>
#include <hip/hip_fp16.h>
#include <math.h>

// ---------------------------------------------------------------------------
// WaveRNN fused, 2 items per 128-thread block (wave-per-item), fp16 LDS +
// v_dot2_f32_f16 convs.  Round-7 body (111 us dispatch) unchanged; the only
// structural change is packing TWO independent waves per workgroup to break
// the 16-workgroups/CU hardware cap that froze occupancy at 49%:
//   LDS/block = 2 x 6416 B ~= 12.9 KB -> 12 blocks/CU x 2 waves = 24 waves/CU.
// __syncthreads now couples 2 symmetric waves (same-length code, tiny skew).
//
// Per-wave LDS slice:  X[1056]h : xbuf (pad16|1016|pad16) -> y2h
//                      (8x[pad3|125|pad4]) -> gis[96]f|ghs[96]f
//                      y1h[2048]h : 4 ch x [pad7|500|pad5]
//                      rnn[20]f, hs[32]f
// Conv weights packed once per launch (pack_weights, 4 blocks) into d_ws as
// zero-padded half2 pairs; consumed at compile-time indices -> s_load path.
// Known poisons avoided: no live-across-phase register staging (R3), no
// half-wave-shfl GRU (R3/R4).
// ---------------------------------------------------------------------------

typedef _Float16 h2 __attribute__((ext_vector_type(2)));
typedef _Float16 h4 __attribute__((ext_vector_type(4)));

__device__ __forceinline__ float fdot2(h2 a, h2 b, float c)
{
#if defined(__has_builtin)
#if __has_builtin(__builtin_amdgcn_fdot2)
    return __builtin_amdgcn_fdot2(a, b, c, false);
#else
    return c + (float)a.x * (float)b.x + (float)a.y * (float)b.y;
#endif
#else
    return c + (float)a.x * (float)b.x + (float)a.y * (float)b.y;
#endif
}

// Pack conv weights into zero-padded half2 pairs in d_ws:
//   [0,64)    w1p: c(4) x 16 pairs, pair j covers taps (2j-1, 2j)   [tap -1 = 0]
//   [64,320)  w2p: (c*4+ci)(32) x 8 pairs, taps (2j, 2j+1), tap 15 = 0
//   [320,832) w3p: (c*8+ci)(128) x 4 pairs, taps (2j, 2j+1), tap 7 = 0
__global__ void pack_weights(const float* __restrict__ w1,
                             const float* __restrict__ w2,
                             const float* __restrict__ w3,
                             h2* __restrict__ ws)
{
    int idx = blockIdx.x * 256 + threadIdx.x;
    if (idx < 832) {
        float f0, f1;
        if (idx < 64) {
            int c = idx >> 4, jp = idx & 15;
            int j0 = 2 * jp, j1 = j0 + 1;
            f0 = (j0 == 0) ? 0.0f : w1[c * 31 + j0 - 1];
            f1 = w1[c * 31 + j1 - 1];
        } else if (idx < 320) {
            int r = idx - 64, cc = r >> 3, jp = r & 7;
            int j0 = 2 * jp, j1 = j0 + 1;
            f0 = w2[cc * 15 + j0];
            f1 = (j1 < 15) ? w2[cc * 15 + j1] : 0.0f;
        } else {
            int r = idx - 320, cc = r >> 2, jp = r & 3;
            int j0 = 2 * jp, j1 = j0 + 1;
            f0 = (j0 < 7) ? w3[cc * 7 + j0] : 0.0f;
            f1 = (j1 < 7) ? w3[cc * 7 + j1] : 0.0f;
        }
        ws[idx] = (h2){(_Float16)f0, (_Float16)f1};
    }
}

// conv1 at position p: window = stored halfs [h0 .. h0+31]; pair j covers
// (h0+2j, h0+2j+1); w1p pair 0 = (0, w[0]) absorbs the odd window start.
__device__ __forceinline__ void conv1_pos(const _Float16* __restrict__ xh,
                                          _Float16* __restrict__ y1h,
                                          const h2* __restrict__ w1p,
                                          const float* __restrict__ b1,
                                          int p, int h0)
{
    const h4* src = (const h4*)(xh + h0);        // byte 2*h0, 8B aligned
    h2 xp[16];
#pragma unroll
    for (int j = 0; j < 8; ++j) {
        h4 v = src[j];
        xp[2 * j]     = (h2){v.x, v.y};
        xp[2 * j + 1] = (h2){v.z, v.w};
    }
    float a0 = b1[0], a1 = b1[1], a2 = b1[2], a3 = b1[3];
#pragma unroll
    for (int j = 0; j < 16; ++j) {
        a0 = fdot2(xp[j], w1p[j],      a0);
        a1 = fdot2(xp[j], w1p[16 + j], a1);
        a2 = fdot2(xp[j], w1p[32 + j], a2);
        a3 = fdot2(xp[j], w1p[48 + j], a3);
    }
    y1h[7 + p]        = (_Float16)fmaxf(a0, 0.0f);
    y1h[512 + 7 + p]  = (_Float16)fmaxf(a1, 0.0f);
    y1h[1024 + 7 + p] = (_Float16)fmaxf(a2, 0.0f);
    y1h[1536 + 7 + p] = (_Float16)fmaxf(a3, 0.0f);
}

__global__ void __launch_bounds__(128, 4)
wavernn_fused(const float* __restrict__ past,      // (B,2000)
              const float* __restrict__ velocity,  // (B,)
              const float* __restrict__ log_pitch, // (B,)
              const float* __restrict__ time_in,   // (B,)
              const float* __restrict__ hidden,    // (B,32)
              const float* __restrict__ b1,
              const float* __restrict__ b2,
              const float* __restrict__ b3,
              const float* __restrict__ w_ih, const float* __restrict__ w_hh,
              const float* __restrict__ b_ih, const float* __restrict__ b_hh,
              const float* __restrict__ w_proj, const float* __restrict__ b_proj,
              const h2* __restrict__ wsp,          // packed conv weights
              float* __restrict__ out, int B)
{
    __shared__ __align__(16) _Float16 Xs[2][1056];    // xbuf -> y2h -> gis|ghs
    __shared__ __align__(16) _Float16 y1hs[2][2048];  // 4 ch x [pad7|500|pad5]
    __shared__ float rnns[2][20];  // [0..15]=ctx, 16=vel, 17=lp, 18=time
    __shared__ float hss[2][32];

    const int w = threadIdx.x >> 6;  // wave id: which item in this block
    const int t = threadIdx.x & 63;  // lane
    const int b = blockIdx.x * 2 + w;

    _Float16* const X    = Xs[w];
    _Float16* const y1h  = y1hs[w];
    float* const rnn     = rnns[w];
    float* const hs      = hss[w];

    _Float16* const xbuf = X;                     // conv1 phase
    _Float16* const y2h  = X;                     // conv2/3 phase
    float* const gis     = (float*)X;             // GRU phase
    float* const ghs     = (float*)X + 96;

    const h2* const w1p = wsp;
    const h2* const w2p = wsp + 64;
    const h2* const w3p = wsp + 320;

    const float4* row4 = (const float4*)(past + (size_t)b * 2000);

    // ---------------- pads + small stages + chunk0 stage ----------------
    if (t < 16) { xbuf[t] = (_Float16)0.0f; xbuf[1032 + t] = (_Float16)0.0f; }
    if (t < 48) { int c = t / 12, k = t % 12;
                  y1h[c * 512 + (k < 7 ? k : 500 + k)] = (_Float16)0.0f; }
    if (t < 32) hs[t] = hidden[(size_t)b * 32 + t];
    if (t == 0) rnn[16] = velocity[b];
    if (t == 1) rnn[17] = log_pitch[b];
    if (t == 2) rnn[18] = time_in[b];

    // chunk0: samples 0..1015 at half idx 16+s (write h4 = 8B aligned)
#pragma unroll
    for (int j = 0; j < 4; ++j) {
        int i = t + 64 * j;
        if (i < 254) {
            float4 q = row4[i];
            h4 hv = {(_Float16)q.x, (_Float16)q.y, (_Float16)q.z, (_Float16)q.w};
            *(h4*)(xbuf + 16 + 4 * i) = hv;
        }
    }
    __syncthreads();

    // ---------------- conv1 chunk 0: positions 0..249, h0 = 4p ----------
#pragma unroll
    for (int j = 0; j < 4; ++j) {
        int p = t + 64 * j;
        if (p < 250) conv1_pos(xbuf, y1h, w1p, b1, p, 4 * p);
    }
    __syncthreads();                     // WAR: all reads of xbuf done

    // ---------------- stage chunk 1: samples 984..1999 at idx 16+(s-984) --
#pragma unroll
    for (int j = 0; j < 4; ++j) {
        int i = t + 64 * j;
        if (i < 254) {
            float4 q = row4[246 + i];
            h4 hv = {(_Float16)q.x, (_Float16)q.y, (_Float16)q.z, (_Float16)q.w};
            *(h4*)(xbuf + 16 + 4 * i) = hv;
        }
    }
    __syncthreads();

    // ---------------- conv1 chunk 1: positions 250..499, h0 = 4p-984 ------
#pragma unroll
    for (int j = 0; j < 4; ++j) {
        int p = 250 + t + 64 * j;
        if (p < 500) conv1_pos(xbuf, y1h, w1p, b1, p, 4 * p - 984);
    }
    __syncthreads();                     // xbuf dead; X becomes y2h

    // ---------------- conv2: 4->8ch, k=15, s=4 (+ y2h pad zeroing) --------
    if (t < 56) { int c = t / 7, k = t % 7;
                  y2h[c * 132 + (k < 3 ? k : 125 + k)] = (_Float16)0.0f; }
#pragma unroll
    for (int jj = 0; jj < 2; ++jj) {
        int p = t + 64 * jj;
        if (p < 125) {
            float acc[8];
#pragma unroll
            for (int c = 0; c < 8; ++c) acc[c] = b2[c];
#pragma unroll
            for (int ci = 0; ci < 4; ++ci) {
                // window = stored halfs [4p .. 4p+15] (taps 0..14 + pad)
                const h4* src = (const h4*)(y1h + 512 * ci + 4 * p);
                h2 xp[8];
#pragma unroll
                for (int j = 0; j < 4; ++j) {
                    h4 v = src[j];
                    xp[2 * j]     = (h2){v.x, v.y};
                    xp[2 * j + 1] = (h2){v.z, v.w};
                }
#pragma unroll
                for (int jp = 0; jp < 8; ++jp) {
#pragma unroll
                    for (int c = 0; c < 8; ++c)
                        acc[c] = fdot2(xp[jp], w2p[(c * 4 + ci) * 8 + jp], acc[c]);
                }
            }
#pragma unroll
            for (int c = 0; c < 8; ++c)
                y2h[c * 132 + 3 + p] = (_Float16)fmaxf(acc[c], 0.0f);
        }
    }
    __syncthreads();

    // ------- conv3: 8->16ch, k=7, s=4 + relu + mean (lanes 0..31) ----------
    if (t < 32) {
        float acc[16];
#pragma unroll
        for (int c = 0; c < 16; ++c) acc[c] = 0.0f;
#pragma unroll
        for (int ci = 0; ci < 8; ++ci) {
            // window = stored halfs [4t .. 4t+7] (taps 0..6 + pad)
            const h4* src = (const h4*)(y2h + 132 * ci + 4 * t);
            h4 v0 = src[0], v1 = src[1];
            h2 xp[4] = {(h2){v0.x, v0.y}, (h2){v0.z, v0.w},
                        (h2){v1.x, v1.y}, (h2){v1.z, v1.w}};
#pragma unroll
            for (int jp = 0; jp < 4; ++jp) {
#pragma unroll
                for (int c = 0; c < 16; ++c)
                    acc[c] = fdot2(xp[jp], w3p[(c * 8 + ci) * 4 + jp], acc[c]);
            }
        }
#pragma unroll
        for (int c = 0; c < 16; ++c) {
            float v = fmaxf(acc[c] + b3[c], 0.0f);
            v += __shfl_xor(v, 16); v += __shfl_xor(v, 8);
            v += __shfl_xor(v, 4);  v += __shfl_xor(v, 2);
            v += __shfl_xor(v, 1);
            if (t == 0) rnn[c] = v * (1.0f / 32.0f);
        }
    }
    __syncthreads();                    // y2h dead; X becomes gis|ghs

    // ---------------- GRU gates (round-2 structure, LDS-based) -------------
    {
        float rv[19];
#pragma unroll
        for (int j = 0; j < 19; ++j) rv[j] = rnn[j];

        float a = b_ih[t];
        const float* wr = w_ih + t * 19;
#pragma unroll
        for (int j = 0; j < 19; ++j) a += rv[j] * wr[j];
        gis[t] = a;
        if (t < 32) {
            float a2 = b_ih[64 + t];
            const float* wr2 = w_ih + (64 + t) * 19;
#pragma unroll
            for (int j = 0; j < 19; ++j) a2 += rv[j] * wr2[j];
            gis[64 + t] = a2;
        }

        float hv[32];
#pragma unroll
        for (int j = 0; j < 32; ++j) hv[j] = hs[j];

        float g = b_hh[t];
        const float4* wh = (const float4*)(w_hh + t * 32);
#pragma unroll
        for (int j = 0; j < 8; ++j) {
            float4 q = wh[j];
            g += hv[4 * j] * q.x + hv[4 * j + 1] * q.y +
                 hv[4 * j + 2] * q.z + hv[4 * j + 3] * q.w;
        }
        ghs[t] = g;
        if (t < 32) {
            float g2 = b_hh[64 + t];
            const float4* wh2 = (const float4*)(w_hh + (64 + t) * 32);
#pragma unroll
            for (int j = 0; j < 8; ++j) {
                float4 q = wh2[j];
                g2 += hv[4 * j] * q.x + hv[4 * j + 1] * q.y +
                      hv[4 * j + 2] * q.z + hv[4 * j + 3] * q.w;
            }
            ghs[64 + t] = g2;
        }
    }
    __syncthreads();

    // ---------------- combine + projection (lanes 0..31) ----------------
    if (t < 32) {
        const int j = t;
        float r = 1.0f / (1.0f + expf(-(gis[j] + ghs[j])));
        float z = 1.0f / (1.0f + expf(-(gis[32 + j] + ghs[32 + j])));
        float n = tanhf(gis[64 + j] + r * ghs[64 + j]);
        float nh = (1.0f - z) * n + z * hs[j];
        out[(size_t)2 * B + (size_t)b * 32 + j] = nh;   // new_hidden

        float p0 = nh * w_proj[j];
        float p1 = nh * w_proj[32 + j];
        p0 += __shfl_xor(p0, 16); p1 += __shfl_xor(p1, 16);
        p0 += __shfl_xor(p0, 8);  p1 += __shfl_xor(p1, 8);
        p0 += __shfl_xor(p0, 4);  p1 += __shfl_xor(p1, 4);
        p0 += __shfl_xor(p0, 2);  p1 += __shfl_xor(p1, 2);
        p0 += __shfl_xor(p0, 1);  p1 += __shfl_xor(p1, 1);
        if (j == 0) {
            out[b] = p0 + b_proj[0];                    // mu
            out[B + b] = expf(p1 + b_proj[1]);          // sigma
        }
    }
}

extern "C" void kernel_launch(void* const* d_in, const int* in_sizes, int n_in,
                              void* d_out, int out_size, void* d_ws, size_t ws_size,
                              hipStream_t stream)
{
    const float* past      = (const float*)d_in[0];
    const float* velocity  = (const float*)d_in[1];
    const float* log_pitch = (const float*)d_in[2];
    const float* time_in   = (const float*)d_in[3];
    const float* hidden    = (const float*)d_in[4];
    const float* w1  = (const float*)d_in[5];
    const float* b1  = (const float*)d_in[6];
    const float* w2  = (const float*)d_in[7];
    const float* b2  = (const float*)d_in[8];
    const float* w3  = (const float*)d_in[9];
    const float* b3  = (const float*)d_in[10];
    const float* wih = (const float*)d_in[11];
    const float* whh = (const float*)d_in[12];
    const float* bih = (const float*)d_in[13];
    const float* bhh = (const float*)d_in[14];
    const float* wpr = (const float*)d_in[15];
    const float* bpr = (const float*)d_in[16];

    const int B = in_sizes[0] / 2000;
    h2* wsp = (h2*)d_ws;

    pack_weights<<<dim3(4), dim3(256), 0, stream>>>(w1, w2, w3, wsp);

    wavernn_fused<<<dim3(B / 2), dim3(128), 0, stream>>>(
        past, velocity, log_pitch, time_in, hidden,
        b1, b2, b3, wih, whh, bih, bhh, wpr, bpr,
        (const h2*)wsp, (float*)d_out, B);
}